// Round 12
// baseline (595.662 us; speedup 1.0000x reference)
//
#include <hip/hip_runtime.h>

#define N_NODES 50000
#define N_EDGES 800000
#define N_GRAPHS 1000
#define NODE_DIMC 128
#define HDIM 256
#define NLAYERS 4
#define NPROPS 3
#define BN_EPSF 1e-5f
#define NBLK 196   // ceil(N_NODES/256)
#define GB 8       // graphs per head-block

typedef __attribute__((ext_vector_type(4))) float f32x4;
typedef __attribute__((ext_vector_type(8))) short short8;
typedef __attribute__((ext_vector_type(8))) unsigned short u16x8;

__device__ __forceinline__ float4 ld4(const float* p){ return *reinterpret_cast<const float4*>(p); }
__device__ __forceinline__ unsigned short f2bf(float f){
  unsigned u = __float_as_uint(f);
  return (unsigned short)((u + 0x7FFFu + ((u >> 16) & 1u)) >> 16);
}
__device__ __forceinline__ float bf2f(unsigned short s){ return __uint_as_float(((unsigned)s) << 16); }

__device__ __forceinline__ void gl2lds16(const void* g, void* l){
  __builtin_amdgcn_global_load_lds((const __attribute__((address_space(1))) unsigned int*)g,
                                   (__attribute__((address_space(3))) unsigned int*)l, 16, 0, 0);
}

// ---------------- fused count + prep ----------------
#define EB 3125                                    // ceil(N_EDGES/256)
#define XCVT_N (N_NODES*NODE_DIMC/4)
#define EMBWT_N (NODE_DIMC*HDIM)
#define GCNWT_N (NLAYERS*HDIM*HDIM)
#define BN_N (NLAYERS*HDIM)
#define PREP_TOTAL (XCVT_N + EMBWT_N + GCNWT_N + BN_N)
#define PREP_BLKS ((PREP_TOTAL + 255)/256)

__global__ void k_countprep(const int* __restrict__ ei, int* __restrict__ cnt,
                            const float* __restrict__ x, unsigned short* __restrict__ xb,
                            const float* __restrict__ embW, unsigned short* __restrict__ embWt,
                            const float* __restrict__ gcnW, unsigned short* __restrict__ gcnWt,
                            const float* __restrict__ gcnb, const float* __restrict__ bng,
                            const float* __restrict__ bnb, const float* __restrict__ bnm,
                            const float* __restrict__ bnv, float* __restrict__ S, float* __restrict__ T){
  int b = blockIdx.x;
  if (b < EB){
    int e = b*256 + threadIdx.x;
    if (e < N_EDGES) atomicAdd(&cnt[ei[N_EDGES + e]], 1);
    return;
  }
  int idx = (b - EB)*256 + threadIdx.x;
  if (idx < XCVT_N){
    float4 v = ld4(x + (size_t)idx*4);
    ushort4 o;
    o.x = f2bf(v.x); o.y = f2bf(v.y); o.z = f2bf(v.z); o.w = f2bf(v.w);
    *reinterpret_cast<ushort4*>(xb + (size_t)idx*4) = o;
    return;
  }
  idx -= XCVT_N;
  if (idx < EMBWT_N){
    int c = idx >> 7, k = idx & 127;
    embWt[idx] = f2bf(embW[(size_t)k*HDIM + c]);
    return;
  }
  idx -= EMBWT_N;
  if (idx < GCNWT_N){
    int l = idx >> 16, rem = idx & 65535;
    int c = rem >> 8, k = rem & 255;
    gcnWt[idx] = f2bf(gcnW[(size_t)l*HDIM*HDIM + (size_t)k*HDIM + c]);
    return;
  }
  idx -= GCNWT_N;
  if (idx < BN_N){
    float s = bng[idx] * rsqrtf(bnv[idx] + BN_EPSF);
    S[idx] = s;
    T[idx] = (gcnb[idx] - bnm[idx]) * s + bnb[idx];
  }
}

// ---------------- scans ----------------
__global__ void k_scan1(const int* __restrict__ cnt, int* __restrict__ rowp, int* __restrict__ part){
  __shared__ int s[256];
  int t = threadIdx.x;
  int i = blockIdx.x*256 + t;
  int v = (i < N_NODES) ? cnt[i] : 0;
  s[t] = v;
  __syncthreads();
  #pragma unroll
  for (int off=1; off<256; off<<=1){
    int x = s[t];
    int y = (t >= off) ? s[t-off] : 0;
    __syncthreads();
    s[t] = x + y;
    __syncthreads();
  }
  if (i < N_NODES) rowp[i+1] = s[t];
  if (t == 255) part[blockIdx.x] = s[255];
}

__global__ void k_scan2(int* __restrict__ part){
  __shared__ int s[256];
  int t = threadIdx.x;
  int v = (t < NBLK) ? part[t] : 0;
  s[t] = v;
  __syncthreads();
  #pragma unroll
  for (int off=1; off<256; off<<=1){
    int x = s[t];
    int y = (t >= off) ? s[t-off] : 0;
    __syncthreads();
    s[t] = x + y;
    __syncthreads();
  }
  if (t < NBLK) part[t] = s[t] - v;   // exclusive offsets
}

__global__ void k_scan3(const int* __restrict__ cnt, int* __restrict__ rowp,
                        const int* __restrict__ part, float* __restrict__ dinv){
  int i = blockIdx.x*256 + threadIdx.x;
  if (i < N_NODES){
    rowp[i+1] += part[blockIdx.x];
    dinv[i] = rsqrtf(1.0f + (float)cnt[i]);
  }
  if (i == 0) rowp[0] = 0;
}

// slot claim via atomicSub on cnt (cnt dead after this kernel; re-built every call)
__global__ void k_fill(const int* __restrict__ ei, const int* __restrict__ rowp, int* __restrict__ cnt,
                       const float* __restrict__ dinv, int2* __restrict__ csr){
  int e = blockIdx.x*256 + threadIdx.x;
  if (e >= N_EDGES) return;
  int sr = ei[e];
  int ds = ei[N_EDGES + e];
  int pos = rowp[ds] + atomicSub(&cnt[ds], 1) - 1;
  csr[pos] = make_int2(sr, __float_as_int(dinv[sr]));
}

// ---------------- bf16 MFMA GEMM: BM=64 x BN=256 (full width), BK=32, dbuf LDS (R11) ----------------
template<int K, bool EMB>
__global__ __launch_bounds__(256) void k_mgemm(const unsigned short* __restrict__ A,
                                               const unsigned short* __restrict__ Wt,
                                               const float* __restrict__ bias,
                                               unsigned short* __restrict__ outp,
                                               int nrows){
  __shared__ unsigned short SMEM[20480];   // 40,960 B
  unsigned short* As0 = SMEM;              // As[buf] = SMEM + buf*2048 (64 rows x 32 k)
  unsigned short* Bs0 = SMEM + 4096;       // Bs[buf] = SMEM + 4096 + buf*8192 (256 cols x 32 k)
  const int t = threadIdx.x;
  const int lane = t & 63;
  const int wid = t >> 6;
  const int row0 = blockIdx.x * 64;
  constexpr int NK = K / 32;

  f32x4 acc[4][4];
  #pragma unroll
  for (int i=0;i<4;i++)
    #pragma unroll
    for (int j=0;j<4;j++) acc[i][j] = (f32x4){0.f,0.f,0.f,0.f};

  auto stage = [&](int buf, int k0){
    {
      int c0 = wid*64;
      int c  = c0 + lane;
      int cs = c ^ ((c >> 3) & 7);
      int r  = cs >> 2;
      int kp = (cs & 3) * 8;
      gl2lds16(A + (size_t)(row0 + r)*K + k0 + kp, As0 + buf*2048 + c0*8);
    }
    #pragma unroll
    for (int i=0;i<4;i++){
      int c0 = (wid*4 + i)*64;
      int c  = c0 + lane;
      int cs = c ^ ((c >> 3) & 7);
      int col = cs >> 2;
      int kp  = (cs & 3) * 8;
      gl2lds16(Wt + (size_t)col*K + k0 + kp, Bs0 + buf*8192 + c0*8);
    }
  };

  stage(0, 0);
  int cur = 0;
  #pragma unroll
  for (int tk = 0; tk < NK; ++tk){
    if (tk + 1 < NK){
      stage(cur ^ 1, (tk+1)*32);
      asm volatile("s_waitcnt vmcnt(5)" ::: "memory");
    } else {
      asm volatile("s_waitcnt vmcnt(0)" ::: "memory");
    }
    __builtin_amdgcn_s_barrier();
    const int kofs = (lane >> 4) * 8;
    short8 af[4], bfv[4];
    #pragma unroll
    for (int mi=0;mi<4;mi++){
      int r = mi*16 + (lane & 15);
      int idx = r*32 + kofs;
      int sw = idx ^ (((idx >> 6) & 7) << 3);
      af[mi] = *reinterpret_cast<const short8*>(As0 + cur*2048 + sw);
    }
    #pragma unroll
    for (int ni=0;ni<4;ni++){
      int col = wid*64 + ni*16 + (lane & 15);
      int idx = col*32 + kofs;
      int sw = idx ^ (((idx >> 6) & 7) << 3);
      bfv[ni] = *reinterpret_cast<const short8*>(Bs0 + cur*8192 + sw);
    }
    #pragma unroll
    for (int mi=0;mi<4;mi++)
      #pragma unroll
      for (int ni=0;ni<4;ni++)
        acc[mi][ni] = __builtin_amdgcn_mfma_f32_16x16x32_bf16(af[mi], bfv[ni], acc[mi][ni], 0, 0, 0);
    __builtin_amdgcn_s_barrier();
    cur ^= 1;
  }

  // epilogue: acc -> CT[64][268] bf16 -> coalesced u16x8 stores
  __syncthreads();
  unsigned short* CT = SMEM;
  #pragma unroll
  for (int mi=0;mi<4;mi++){
    #pragma unroll
    for (int j=0;j<4;j++){
      int rl = mi*16 + (lane >> 4)*4 + j;
      #pragma unroll
      for (int ni=0;ni<4;ni++){
        float v = acc[mi][ni][j];
        int cl = wid*64 + ni*16 + (lane & 15);
        if (EMB) v = fmaxf(v + bias[cl], 0.f);
        CT[rl*268 + cl] = f2bf(v);
      }
    }
  }
  __syncthreads();
  #pragma unroll
  for (int it=0; it<8; ++it){
    int cidx = t + it*256;
    int rl = cidx >> 5;
    int ck = cidx & 31;
    int gr = row0 + rl;
    if (gr < nrows){
      u16x8 v = *reinterpret_cast<const u16x8*>(CT + rl*268 + ck*8);
      *reinterpret_cast<u16x8*>(outp + (size_t)gr*HDIM + ck*8) = v;
    }
  }
}

// ---------------- fused aggregation: half-wave edge split, 4-deep, bf16 h (R8) ----------------
__global__ __launch_bounds__(256) void k_agg(const unsigned short* __restrict__ m, const int* __restrict__ rowp,
                                             const int2* __restrict__ csr,
                                             const float* __restrict__ S, const float* __restrict__ T,
                                             unsigned short* __restrict__ h){
  int node = blockIdx.x*4 + (threadIdx.x >> 6);
  int lane = threadIdx.x & 63;
  int half = lane >> 5;
  int c = (lane & 31) * 8;

  int s = rowp[node], e = rowp[node+1];
  float dn = rsqrtf(1.0f + (float)(e - s));   // deg = 1 + in-degree

  float acc[8];
  const size_t base = (size_t)node*HDIM + c;
  if (half == 0){
    u16x8 ms = *reinterpret_cast<const u16x8*>(m + base);
    #pragma unroll
    for (int j=0;j<8;j++) acc[j] = bf2f(ms[j]) * dn;
  } else {
    #pragma unroll
    for (int j=0;j<8;j++) acc[j] = 0.f;
  }

  int i = s + half;
  for (; i + 6 < e; i += 8){
    int2 e0 = csr[i], e1 = csr[i+2], e2 = csr[i+4], e3 = csr[i+6];
    float w0 = __int_as_float(e0.y), w1 = __int_as_float(e1.y);
    float w2 = __int_as_float(e2.y), w3 = __int_as_float(e3.y);
    u16x8 m0 = *reinterpret_cast<const u16x8*>(m + (size_t)e0.x*HDIM + c);
    u16x8 m1 = *reinterpret_cast<const u16x8*>(m + (size_t)e1.x*HDIM + c);
    u16x8 m2 = *reinterpret_cast<const u16x8*>(m + (size_t)e2.x*HDIM + c);
    u16x8 m3 = *reinterpret_cast<const u16x8*>(m + (size_t)e3.x*HDIM + c);
    #pragma unroll
    for (int j=0;j<8;j++){
      acc[j] += w0*bf2f(m0[j]) + w1*bf2f(m1[j]);
      acc[j] += w2*bf2f(m2[j]) + w3*bf2f(m3[j]);
    }
  }
  if (i + 2 < e){
    int2 e0 = csr[i], e1 = csr[i+2];
    float w0 = __int_as_float(e0.y), w1 = __int_as_float(e1.y);
    u16x8 m0 = *reinterpret_cast<const u16x8*>(m + (size_t)e0.x*HDIM + c);
    u16x8 m1 = *reinterpret_cast<const u16x8*>(m + (size_t)e1.x*HDIM + c);
    #pragma unroll
    for (int j=0;j<8;j++) acc[j] += w0*bf2f(m0[j]) + w1*bf2f(m1[j]);
    i += 4;
  }
  if (i < e){
    int2 e0 = csr[i];
    float w0 = __int_as_float(e0.y);
    u16x8 m0 = *reinterpret_cast<const u16x8*>(m + (size_t)e0.x*HDIM + c);
    #pragma unroll
    for (int j=0;j<8;j++) acc[j] += w0*bf2f(m0[j]);
  }

  #pragma unroll
  for (int j=0;j<8;j++) acc[j] += __shfl_xor(acc[j], 32);

  if (half == 0){
    float4 S0 = ld4(S + c), S1 = ld4(S + c + 4);
    float4 T0 = ld4(T + c), T1 = ld4(T + c + 4);
    u16x8 hold = *reinterpret_cast<const u16x8*>(h + base);
    float Sv[8] = {S0.x,S0.y,S0.z,S0.w,S1.x,S1.y,S1.z,S1.w};
    float Tv[8] = {T0.x,T0.y,T0.z,T0.w,T1.x,T1.y,T1.z,T1.w};
    u16x8 ob;
    #pragma unroll
    for (int j=0;j<8;j++){
      float o = fmaxf(acc[j]*dn*Sv[j] + Tv[j], 0.f) + bf2f(hold[j]);
      ob[j] = f2bf(o);
    }
    *reinterpret_cast<u16x8*>(h + base) = ob;
  }
}

// ---------------- fused pool + 3-layer heads (GB graphs per block) ----------------
__device__ __forceinline__ int lbound(const int* __restrict__ a, int n, int key){
  int lo = 0, hi = n;
  while (lo < hi){ int mid = (lo + hi) >> 1; if (a[mid] < key) lo = mid + 1; else hi = mid; }
  return lo;
}

__global__ __launch_bounds__(128) void k_poolheads(const unsigned short* __restrict__ h,
                                                   const int* __restrict__ batch,
                                                   const float* __restrict__ W1, const float* __restrict__ b1,
                                                   const float* __restrict__ W2, const float* __restrict__ b2,
                                                   const float* __restrict__ W3, const float* __restrict__ b3,
                                                   float* __restrict__ out){
  int g0 = blockIdx.x * GB;
  __shared__ float gs[GB][HDIM];
  __shared__ float z1[GB][128];
  int t = threadIdx.x;

  // pool: thread t handles channels 2t, 2t+1 for each graph
  #pragma unroll
  for (int gi=0; gi<GB; gi++){
    int lo = lbound(batch, N_NODES, g0+gi);
    int hi = lbound(batch, N_NODES, g0+gi+1);
    float s0 = 0.f, s1 = 0.f;
    for (int n = lo; n < hi; ++n){
      unsigned u = *reinterpret_cast<const unsigned*>(h + (size_t)n*HDIM + 2*t);
      s0 += bf2f((unsigned short)(u & 0xffffu));
      s1 += bf2f((unsigned short)(u >> 16));
    }
    float inv = 1.0f / fmaxf((float)(hi - lo), 1.0f);
    gs[gi][2*t]   = s0 * inv;
    gs[gi][2*t+1] = s1 * inv;
  }
  __syncthreads();

  for (int p=0; p<NPROPS; ++p){
    const float* w1 = W1 + (size_t)p*HDIM*128;
    float a[GB];
    #pragma unroll
    for (int gi=0; gi<GB; gi++) a[gi] = 0.f;
    for (int i=0;i<HDIM;i++){
      float wv = w1[(size_t)i*128 + t];
      #pragma unroll
      for (int gi=0; gi<GB; gi++) a[gi] += gs[gi][i] * wv;
    }
    float b1v = b1[p*128 + t];
    #pragma unroll
    for (int gi=0; gi<GB; gi++) z1[gi][t] = fmaxf(a[gi] + b1v, 0.f);
    __syncthreads();

    if (t < 64){
      const float* w2 = W2 + (size_t)p*128*64;
      float a2[GB];
      #pragma unroll
      for (int gi=0; gi<GB; gi++) a2[gi] = 0.f;
      for (int i=0;i<128;i++){
        float wv = w2[(size_t)i*64 + t];
        #pragma unroll
        for (int gi=0; gi<GB; gi++) a2[gi] += z1[gi][i] * wv;
      }
      float w3v = W3[p*64 + t];
      float b2v = b2[p*64 + t];
      float b3v = b3[p];
      #pragma unroll
      for (int gi=0; gi<GB; gi++){
        float z2 = fmaxf(a2[gi] + b2v, 0.f);
        float v = z2 * w3v;
        #pragma unroll
        for (int off=32; off>0; off>>=1) v += __shfl_down(v, off, 64);
        if (t == 0) out[(size_t)(g0+gi)*NPROPS + p] = v + b3v;
      }
    }
    __syncthreads();
  }
}

// ---------------- launch ----------------
extern "C" void kernel_launch(void* const* d_in, const int* in_sizes, int n_in,
                              void* d_out, int out_size, void* d_ws, size_t ws_size,
                              hipStream_t stream){
  const float* x     = (const float*)d_in[0];
  const int*   ei    = (const int*)  d_in[1];
  const int*   batch = (const int*)  d_in[2];
  const float* embW  = (const float*)d_in[3];
  const float* embb  = (const float*)d_in[4];
  const float* gcnW  = (const float*)d_in[5];
  const float* gcnb  = (const float*)d_in[6];
  const float* bng   = (const float*)d_in[7];
  const float* bnb   = (const float*)d_in[8];
  const float* bnm   = (const float*)d_in[9];
  const float* bnv   = (const float*)d_in[10];
  const float* h1W   = (const float*)d_in[11];
  const float* h1b   = (const float*)d_in[12];
  const float* h2W   = (const float*)d_in[13];
  const float* h2b   = (const float*)d_in[14];
  const float* h3W   = (const float*)d_in[15];
  const float* h3b   = (const float*)d_in[16];
  float* out = (float*)d_out;

  char* w = (char*)d_ws;
  auto alloc = [&](size_t bytes)->char*{ char* p = w; w += (bytes + 255) & ~(size_t)255; return p; };
  unsigned short* h    = (unsigned short*)alloc((size_t)N_NODES*HDIM*2);   // bf16 h
  unsigned short* m    = (unsigned short*)alloc((size_t)N_NODES*HDIM*2);   // bf16 messages; reused as xb
  int*   cnt  = (int*)  alloc((size_t)N_NODES*4);
  int*   rowp = (int*)  alloc((size_t)(N_NODES+1)*4);
  float* dinv = (float*)alloc((size_t)N_NODES*4);
  int2*  csr  = (int2*) alloc((size_t)N_EDGES*8);
  int*   part = (int*)  alloc(1024);
  unsigned short* embWt = (unsigned short*)alloc((size_t)NODE_DIMC*HDIM*2);
  unsigned short* gcnWt = (unsigned short*)alloc((size_t)NLAYERS*HDIM*HDIM*2);
  float* bnS  = (float*)alloc((size_t)NLAYERS*HDIM*4);
  float* bnT  = (float*)alloc((size_t)NLAYERS*HDIM*4);

  hipMemsetAsync(cnt, 0, (size_t)N_NODES*4, stream);

  unsigned short* xb = m;
  k_countprep<<<EB + PREP_BLKS,256,0,stream>>>(ei, cnt, x, xb, embW, embWt, gcnW, gcnWt,
                                               gcnb, bng, bnb, bnm, bnv, bnS, bnT);
  k_scan1<<<NBLK,256,0,stream>>>(cnt, rowp, part);
  k_scan2<<<1,256,0,stream>>>(part);
  k_scan3<<<NBLK,256,0,stream>>>(cnt, rowp, part, dinv);
  k_fill<<<EB,256,0,stream>>>(ei, rowp, cnt, dinv, csr);

  const int RB64 = (N_NODES + 63)/64;   // 782 blocks, full-width tiles
  k_mgemm<NODE_DIMC, true><<<RB64,256,0,stream>>>(xb, embWt, embb, h, N_NODES);

  for (int l = 0; l < NLAYERS; ++l){
    k_mgemm<HDIM, false><<<RB64,256,0,stream>>>(h, gcnWt + (size_t)l*HDIM*HDIM, nullptr, m, N_NODES);
    k_agg<<<(N_NODES+3)/4,256,0,stream>>>(m, rowp, csr, bnS + l*HDIM, bnT + l*HDIM, h);
  }

  k_poolheads<<<N_GRAPHS/GB,128,0,stream>>>(h, batch, h1W, h1b, h2W, h2b, h3W, h3b, out);
}

// Round 13
// 468.700 us; speedup vs baseline: 1.2709x; 1.2709x over previous
//
#include <hip/hip_runtime.h>

#define N_NODES 50000
#define N_EDGES 800000
#define N_GRAPHS 1000
#define NODE_DIMC 128
#define HDIM 256
#define NLAYERS 4
#define NPROPS 3
#define BN_EPSF 1e-5f
#define NBLK 196   // ceil(N_NODES/256)
#define GB 8       // graphs per head-block

typedef __attribute__((ext_vector_type(4))) float f32x4;
typedef __attribute__((ext_vector_type(8))) short short8;
typedef __attribute__((ext_vector_type(8))) unsigned short u16x8;

__device__ __forceinline__ float4 ld4(const float* p){ return *reinterpret_cast<const float4*>(p); }
__device__ __forceinline__ unsigned short f2bf(float f){
  unsigned u = __float_as_uint(f);
  return (unsigned short)((u + 0x7FFFu + ((u >> 16) & 1u)) >> 16);
}
__device__ __forceinline__ float bf2f(unsigned short s){ return __uint_as_float(((unsigned)s) << 16); }

__device__ __forceinline__ void gl2lds16(const void* g, void* l){
  __builtin_amdgcn_global_load_lds((const __attribute__((address_space(1))) unsigned int*)g,
                                   (__attribute__((address_space(3))) unsigned int*)l, 16, 0, 0);
}

// ---------------- fused count + prep ----------------
#define EB 3125                                    // ceil(N_EDGES/256)
#define XCVT_N (N_NODES*NODE_DIMC/4)
#define EMBWT_N (NODE_DIMC*HDIM)
#define GCNWT_N (NLAYERS*HDIM*HDIM)
#define BN_N (NLAYERS*HDIM)
#define PREP_TOTAL (XCVT_N + EMBWT_N + GCNWT_N + BN_N)
#define PREP_BLKS ((PREP_TOTAL + 255)/256)

__global__ void k_countprep(const int* __restrict__ ei, int* __restrict__ cnt,
                            const float* __restrict__ x, unsigned short* __restrict__ xb,
                            const float* __restrict__ embW, unsigned short* __restrict__ embWt,
                            const float* __restrict__ gcnW, unsigned short* __restrict__ gcnWt,
                            const float* __restrict__ gcnb, const float* __restrict__ bng,
                            const float* __restrict__ bnb, const float* __restrict__ bnm,
                            const float* __restrict__ bnv, float* __restrict__ S, float* __restrict__ T){
  int b = blockIdx.x;
  if (b < EB){
    int e = b*256 + threadIdx.x;
    if (e < N_EDGES) atomicAdd(&cnt[ei[N_EDGES + e]], 1);
    return;
  }
  int idx = (b - EB)*256 + threadIdx.x;
  if (idx < XCVT_N){
    float4 v = ld4(x + (size_t)idx*4);
    ushort4 o;
    o.x = f2bf(v.x); o.y = f2bf(v.y); o.z = f2bf(v.z); o.w = f2bf(v.w);
    *reinterpret_cast<ushort4*>(xb + (size_t)idx*4) = o;
    return;
  }
  idx -= XCVT_N;
  if (idx < EMBWT_N){
    int c = idx >> 7, k = idx & 127;
    embWt[idx] = f2bf(embW[(size_t)k*HDIM + c]);
    return;
  }
  idx -= EMBWT_N;
  if (idx < GCNWT_N){
    int l = idx >> 16, rem = idx & 65535;
    int c = rem >> 8, k = rem & 255;
    gcnWt[idx] = f2bf(gcnW[(size_t)l*HDIM*HDIM + (size_t)k*HDIM + c]);
    return;
  }
  idx -= GCNWT_N;
  if (idx < BN_N){
    float s = bng[idx] * rsqrtf(bnv[idx] + BN_EPSF);
    S[idx] = s;
    T[idx] = (gcnb[idx] - bnm[idx]) * s + bnb[idx];
  }
}

// ---------------- scans ----------------
__global__ void k_scan1(const int* __restrict__ cnt, int* __restrict__ rowp, int* __restrict__ part){
  __shared__ int s[256];
  int t = threadIdx.x;
  int i = blockIdx.x*256 + t;
  int v = (i < N_NODES) ? cnt[i] : 0;
  s[t] = v;
  __syncthreads();
  #pragma unroll
  for (int off=1; off<256; off<<=1){
    int x = s[t];
    int y = (t >= off) ? s[t-off] : 0;
    __syncthreads();
    s[t] = x + y;
    __syncthreads();
  }
  if (i < N_NODES) rowp[i+1] = s[t];
  if (t == 255) part[blockIdx.x] = s[255];
}

__global__ void k_scan2(int* __restrict__ part){
  __shared__ int s[256];
  int t = threadIdx.x;
  int v = (t < NBLK) ? part[t] : 0;
  s[t] = v;
  __syncthreads();
  #pragma unroll
  for (int off=1; off<256; off<<=1){
    int x = s[t];
    int y = (t >= off) ? s[t-off] : 0;
    __syncthreads();
    s[t] = x + y;
    __syncthreads();
  }
  if (t < NBLK) part[t] = s[t] - v;   // exclusive offsets
}

__global__ void k_scan3(const int* __restrict__ cnt, int* __restrict__ rowp,
                        const int* __restrict__ part, float* __restrict__ dinv){
  int i = blockIdx.x*256 + threadIdx.x;
  if (i < N_NODES){
    rowp[i+1] += part[blockIdx.x];
    dinv[i] = rsqrtf(1.0f + (float)cnt[i]);
  }
  if (i == 0) rowp[0] = 0;
}

// slot claim via atomicSub on cnt (cnt dead after this kernel; re-built every call)
__global__ void k_fill(const int* __restrict__ ei, const int* __restrict__ rowp, int* __restrict__ cnt,
                       const float* __restrict__ dinv, int2* __restrict__ csr){
  int e = blockIdx.x*256 + threadIdx.x;
  if (e >= N_EDGES) return;
  int sr = ei[e];
  int ds = ei[N_EDGES + e];
  int pos = rowp[ds] + atomicSub(&cnt[ds], 1) - 1;
  csr[pos] = make_int2(sr, __float_as_int(dinv[sr]));
}

// ---------------- bf16 MFMA GEMM: BM=64 x BN=256 (full width), BK=32, dbuf LDS (R11) ----------------
template<int K, bool EMB>
__global__ __launch_bounds__(256) void k_mgemm(const unsigned short* __restrict__ A,
                                               const unsigned short* __restrict__ Wt,
                                               const float* __restrict__ bias,
                                               unsigned short* __restrict__ outp,
                                               int nrows){
  __shared__ unsigned short SMEM[20480];   // 40,960 B
  unsigned short* As0 = SMEM;              // As[buf] = SMEM + buf*2048 (64 rows x 32 k)
  unsigned short* Bs0 = SMEM + 4096;       // Bs[buf] = SMEM + 4096 + buf*8192 (256 cols x 32 k)
  const int t = threadIdx.x;
  const int lane = t & 63;
  const int wid = t >> 6;
  const int row0 = blockIdx.x * 64;
  constexpr int NK = K / 32;

  f32x4 acc[4][4];
  #pragma unroll
  for (int i=0;i<4;i++)
    #pragma unroll
    for (int j=0;j<4;j++) acc[i][j] = (f32x4){0.f,0.f,0.f,0.f};

  auto stage = [&](int buf, int k0){
    {
      int c0 = wid*64;
      int c  = c0 + lane;
      int cs = c ^ ((c >> 3) & 7);
      int r  = cs >> 2;
      int kp = (cs & 3) * 8;
      gl2lds16(A + (size_t)(row0 + r)*K + k0 + kp, As0 + buf*2048 + c0*8);
    }
    #pragma unroll
    for (int i=0;i<4;i++){
      int c0 = (wid*4 + i)*64;
      int c  = c0 + lane;
      int cs = c ^ ((c >> 3) & 7);
      int col = cs >> 2;
      int kp  = (cs & 3) * 8;
      gl2lds16(Wt + (size_t)col*K + k0 + kp, Bs0 + buf*8192 + c0*8);
    }
  };

  stage(0, 0);
  int cur = 0;
  #pragma unroll
  for (int tk = 0; tk < NK; ++tk){
    if (tk + 1 < NK){
      stage(cur ^ 1, (tk+1)*32);
      asm volatile("s_waitcnt vmcnt(5)" ::: "memory");
    } else {
      asm volatile("s_waitcnt vmcnt(0)" ::: "memory");
    }
    __builtin_amdgcn_s_barrier();
    const int kofs = (lane >> 4) * 8;
    short8 af[4], bfv[4];
    #pragma unroll
    for (int mi=0;mi<4;mi++){
      int r = mi*16 + (lane & 15);
      int idx = r*32 + kofs;
      int sw = idx ^ (((idx >> 6) & 7) << 3);
      af[mi] = *reinterpret_cast<const short8*>(As0 + cur*2048 + sw);
    }
    #pragma unroll
    for (int ni=0;ni<4;ni++){
      int col = wid*64 + ni*16 + (lane & 15);
      int idx = col*32 + kofs;
      int sw = idx ^ (((idx >> 6) & 7) << 3);
      bfv[ni] = *reinterpret_cast<const short8*>(Bs0 + cur*8192 + sw);
    }
    #pragma unroll
    for (int mi=0;mi<4;mi++)
      #pragma unroll
      for (int ni=0;ni<4;ni++)
        acc[mi][ni] = __builtin_amdgcn_mfma_f32_16x16x32_bf16(af[mi], bfv[ni], acc[mi][ni], 0, 0, 0);
    __builtin_amdgcn_s_barrier();
    cur ^= 1;
  }

  // epilogue: acc -> CT[64][268] bf16 -> coalesced u16x8 stores
  __syncthreads();
  unsigned short* CT = SMEM;
  #pragma unroll
  for (int mi=0;mi<4;mi++){
    #pragma unroll
    for (int j=0;j<4;j++){
      int rl = mi*16 + (lane >> 4)*4 + j;
      #pragma unroll
      for (int ni=0;ni<4;ni++){
        float v = acc[mi][ni][j];
        int cl = wid*64 + ni*16 + (lane & 15);
        if (EMB) v = fmaxf(v + bias[cl], 0.f);
        CT[rl*268 + cl] = f2bf(v);
      }
    }
  }
  __syncthreads();
  #pragma unroll
  for (int it=0; it<8; ++it){
    int cidx = t + it*256;
    int rl = cidx >> 5;
    int ck = cidx & 31;
    int gr = row0 + rl;
    if (gr < nrows){
      u16x8 v = *reinterpret_cast<const u16x8*>(CT + rl*268 + ck*8);
      *reinterpret_cast<u16x8*>(outp + (size_t)gr*HDIM + ck*8) = v;
    }
  }
}

// ---------------- fused aggregation: half-wave edge split, 4-deep, bf16 h (R8) ----------------
__global__ __launch_bounds__(256) void k_agg(const unsigned short* __restrict__ m, const int* __restrict__ rowp,
                                             const int2* __restrict__ csr,
                                             const float* __restrict__ S, const float* __restrict__ T,
                                             unsigned short* __restrict__ h){
  int node = blockIdx.x*4 + (threadIdx.x >> 6);
  int lane = threadIdx.x & 63;
  int half = lane >> 5;
  int c = (lane & 31) * 8;

  int s = rowp[node], e = rowp[node+1];
  float dn = rsqrtf(1.0f + (float)(e - s));   // deg = 1 + in-degree

  float acc[8];
  const size_t base = (size_t)node*HDIM + c;
  if (half == 0){
    u16x8 ms = *reinterpret_cast<const u16x8*>(m + base);
    #pragma unroll
    for (int j=0;j<8;j++) acc[j] = bf2f(ms[j]) * dn;
  } else {
    #pragma unroll
    for (int j=0;j<8;j++) acc[j] = 0.f;
  }

  int i = s + half;
  for (; i + 6 < e; i += 8){
    int2 e0 = csr[i], e1 = csr[i+2], e2 = csr[i+4], e3 = csr[i+6];
    float w0 = __int_as_float(e0.y), w1 = __int_as_float(e1.y);
    float w2 = __int_as_float(e2.y), w3 = __int_as_float(e3.y);
    u16x8 m0 = *reinterpret_cast<const u16x8*>(m + (size_t)e0.x*HDIM + c);
    u16x8 m1 = *reinterpret_cast<const u16x8*>(m + (size_t)e1.x*HDIM + c);
    u16x8 m2 = *reinterpret_cast<const u16x8*>(m + (size_t)e2.x*HDIM + c);
    u16x8 m3 = *reinterpret_cast<const u16x8*>(m + (size_t)e3.x*HDIM + c);
    #pragma unroll
    for (int j=0;j<8;j++){
      acc[j] += w0*bf2f(m0[j]) + w1*bf2f(m1[j]);
      acc[j] += w2*bf2f(m2[j]) + w3*bf2f(m3[j]);
    }
  }
  if (i + 2 < e){
    int2 e0 = csr[i], e1 = csr[i+2];
    float w0 = __int_as_float(e0.y), w1 = __int_as_float(e1.y);
    u16x8 m0 = *reinterpret_cast<const u16x8*>(m + (size_t)e0.x*HDIM + c);
    u16x8 m1 = *reinterpret_cast<const u16x8*>(m + (size_t)e1.x*HDIM + c);
    #pragma unroll
    for (int j=0;j<8;j++) acc[j] += w0*bf2f(m0[j]) + w1*bf2f(m1[j]);
    i += 4;
  }
  if (i < e){
    int2 e0 = csr[i];
    float w0 = __int_as_float(e0.y);
    u16x8 m0 = *reinterpret_cast<const u16x8*>(m + (size_t)e0.x*HDIM + c);
    #pragma unroll
    for (int j=0;j<8;j++) acc[j] += w0*bf2f(m0[j]);
  }

  #pragma unroll
  for (int j=0;j<8;j++) acc[j] += __shfl_xor(acc[j], 32);

  if (half == 0){
    float4 S0 = ld4(S + c), S1 = ld4(S + c + 4);
    float4 T0 = ld4(T + c), T1 = ld4(T + c + 4);
    u16x8 hold = *reinterpret_cast<const u16x8*>(h + base);
    float Sv[8] = {S0.x,S0.y,S0.z,S0.w,S1.x,S1.y,S1.z,S1.w};
    float Tv[8] = {T0.x,T0.y,T0.z,T0.w,T1.x,T1.y,T1.z,T1.w};
    u16x8 ob;
    #pragma unroll
    for (int j=0;j<8;j++){
      float o = fmaxf(acc[j]*dn*Sv[j] + Tv[j], 0.f) + bf2f(hold[j]);
      ob[j] = f2bf(o);
    }
    *reinterpret_cast<u16x8*>(h + base) = ob;
  }
}

// ---------------- global mean pool (batch_idx sorted), bf16 h ----------------
__device__ __forceinline__ int lbound(const int* __restrict__ a, int n, int key){
  int lo = 0, hi = n;
  while (lo < hi){ int mid = (lo + hi) >> 1; if (a[mid] < key) lo = mid + 1; else hi = mid; }
  return lo;
}

__global__ __launch_bounds__(128) void k_pool(const unsigned short* __restrict__ h, const int* __restrict__ batch,
                                              float* __restrict__ g){
  int gi = blockIdx.x;
  int lo = lbound(batch, N_NODES, gi);
  int hi = lbound(batch, N_NODES, gi + 1);
  int t = threadIdx.x;
  float s0 = 0.f, s1 = 0.f;
  for (int n = lo; n < hi; ++n){
    unsigned u = *reinterpret_cast<const unsigned*>(h + (size_t)n*HDIM + 2*t);
    s0 += bf2f((unsigned short)(u & 0xffffu));
    s1 += bf2f((unsigned short)(u >> 16));
  }
  float inv = 1.0f / fmaxf((float)(hi - lo), 1.0f);
  g[(size_t)gi*HDIM + 2*t]     = s0 * inv;
  g[(size_t)gi*HDIM + 2*t + 1] = s1 * inv;
}

// ---------------- fused 3-layer property heads, GB graphs per block ----------------
__global__ __launch_bounds__(128) void k_heads(const float* __restrict__ g,
                                               const float* __restrict__ W1, const float* __restrict__ b1,
                                               const float* __restrict__ W2, const float* __restrict__ b2,
                                               const float* __restrict__ W3, const float* __restrict__ b3,
                                               float* __restrict__ out){
  int g0 = blockIdx.x * GB, p = blockIdx.y;
  __shared__ float gs[GB][HDIM];
  __shared__ float z1[GB][128];
  int t = threadIdx.x;
  #pragma unroll
  for (int gi=0; gi<GB; gi++){
    gs[gi][t]       = g[(size_t)(g0+gi)*HDIM + t];
    gs[gi][t + 128] = g[(size_t)(g0+gi)*HDIM + t + 128];
  }
  __syncthreads();

  const float* w1 = W1 + (size_t)p*HDIM*128;
  float a[GB];
  #pragma unroll
  for (int gi=0; gi<GB; gi++) a[gi] = 0.f;
  for (int i=0;i<HDIM;i++){
    float wv = w1[(size_t)i*128 + t];
    #pragma unroll
    for (int gi=0; gi<GB; gi++) a[gi] += gs[gi][i] * wv;
  }
  float b1v = b1[p*128 + t];
  #pragma unroll
  for (int gi=0; gi<GB; gi++) z1[gi][t] = fmaxf(a[gi] + b1v, 0.f);
  __syncthreads();

  if (t < 64){
    const float* w2 = W2 + (size_t)p*128*64;
    float a2[GB];
    #pragma unroll
    for (int gi=0; gi<GB; gi++) a2[gi] = 0.f;
    for (int i=0;i<128;i++){
      float wv = w2[(size_t)i*64 + t];
      #pragma unroll
      for (int gi=0; gi<GB; gi++) a2[gi] += z1[gi][i] * wv;
    }
    float w3v = W3[p*64 + t];
    float b2v = b2[p*64 + t];
    float b3v = b3[p];
    #pragma unroll
    for (int gi=0; gi<GB; gi++){
      float z2 = fmaxf(a2[gi] + b2v, 0.f);
      float v = z2 * w3v;
      #pragma unroll
      for (int off=32; off>0; off>>=1) v += __shfl_down(v, off, 64);
      if (t == 0) out[(size_t)(g0+gi)*NPROPS + p] = v + b3v;
    }
  }
}

// ---------------- launch ----------------
extern "C" void kernel_launch(void* const* d_in, const int* in_sizes, int n_in,
                              void* d_out, int out_size, void* d_ws, size_t ws_size,
                              hipStream_t stream){
  const float* x     = (const float*)d_in[0];
  const int*   ei    = (const int*)  d_in[1];
  const int*   batch = (const int*)  d_in[2];
  const float* embW  = (const float*)d_in[3];
  const float* embb  = (const float*)d_in[4];
  const float* gcnW  = (const float*)d_in[5];
  const float* gcnb  = (const float*)d_in[6];
  const float* bng   = (const float*)d_in[7];
  const float* bnb   = (const float*)d_in[8];
  const float* bnm   = (const float*)d_in[9];
  const float* bnv   = (const float*)d_in[10];
  const float* h1W   = (const float*)d_in[11];
  const float* h1b   = (const float*)d_in[12];
  const float* h2W   = (const float*)d_in[13];
  const float* h2b   = (const float*)d_in[14];
  const float* h3W   = (const float*)d_in[15];
  const float* h3b   = (const float*)d_in[16];
  float* out = (float*)d_out;

  char* w = (char*)d_ws;
  auto alloc = [&](size_t bytes)->char*{ char* p = w; w += (bytes + 255) & ~(size_t)255; return p; };
  unsigned short* h    = (unsigned short*)alloc((size_t)N_NODES*HDIM*2);   // bf16 h
  unsigned short* m    = (unsigned short*)alloc((size_t)N_NODES*HDIM*2);   // bf16 messages; reused as xb
  int*   cnt  = (int*)  alloc((size_t)N_NODES*4);
  int*   rowp = (int*)  alloc((size_t)(N_NODES+1)*4);
  float* dinv = (float*)alloc((size_t)N_NODES*4);
  int2*  csr  = (int2*) alloc((size_t)N_EDGES*8);
  int*   part = (int*)  alloc(1024);
  float* gp   = (float*)alloc((size_t)N_GRAPHS*HDIM*4);
  unsigned short* embWt = (unsigned short*)alloc((size_t)NODE_DIMC*HDIM*2);
  unsigned short* gcnWt = (unsigned short*)alloc((size_t)NLAYERS*HDIM*HDIM*2);
  float* bnS  = (float*)alloc((size_t)NLAYERS*HDIM*4);
  float* bnT  = (float*)alloc((size_t)NLAYERS*HDIM*4);

  hipMemsetAsync(cnt, 0, (size_t)N_NODES*4, stream);

  unsigned short* xb = m;
  k_countprep<<<EB + PREP_BLKS,256,0,stream>>>(ei, cnt, x, xb, embW, embWt, gcnW, gcnWt,
                                               gcnb, bng, bnb, bnm, bnv, bnS, bnT);
  k_scan1<<<NBLK,256,0,stream>>>(cnt, rowp, part);
  k_scan2<<<1,256,0,stream>>>(part);
  k_scan3<<<NBLK,256,0,stream>>>(cnt, rowp, part, dinv);
  k_fill<<<EB,256,0,stream>>>(ei, rowp, cnt, dinv, csr);

  const int RB64 = (N_NODES + 63)/64;   // 782 blocks, full-width tiles
  k_mgemm<NODE_DIMC, true><<<RB64,256,0,stream>>>(xb, embWt, embb, h, N_NODES);

  for (int l = 0; l < NLAYERS; ++l){
    k_mgemm<HDIM, false><<<RB64,256,0,stream>>>(h, gcnWt + (size_t)l*HDIM*HDIM, nullptr, m, N_NODES);
    k_agg<<<(N_NODES+3)/4,256,0,stream>>>(m, rowp, csr, bnS + l*HDIM, bnT + l*HDIM, h);
  }

  k_pool<<<N_GRAPHS,128,0,stream>>>(h, batch, gp);
  k_heads<<<dim3((N_GRAPHS+GB-1)/GB,NPROPS),128,0,stream>>>(gp, h1W, h1b, h2W, h2b, h3W, h3b, out);
}

// Round 14
// 384.432 us; speedup vs baseline: 1.5495x; 1.2192x over previous
//
#include <hip/hip_runtime.h>

#define N_NODES 50000
#define N_EDGES 800000
#define N_GRAPHS 1000
#define NODE_DIMC 128
#define HDIM 256
#define NLAYERS 4
#define NPROPS 3
#define BN_EPSF 1e-5f
#define NBLK 196   // ceil(N_NODES/256)
#define GB 8       // graphs per head-block

typedef __attribute__((ext_vector_type(4))) float f32x4;
typedef __attribute__((ext_vector_type(2))) float f32x2;
typedef __attribute__((ext_vector_type(8))) short short8;
typedef __attribute__((ext_vector_type(8))) unsigned short u16x8;

__device__ __forceinline__ float4 ld4(const float* p){ return *reinterpret_cast<const float4*>(p); }
__device__ __forceinline__ unsigned short f2bf(float f){
  unsigned u = __float_as_uint(f);
  return (unsigned short)((u + 0x7FFFu + ((u >> 16) & 1u)) >> 16);
}
__device__ __forceinline__ float bf2f(unsigned short s){ return __uint_as_float(((unsigned)s) << 16); }

__device__ __forceinline__ void gl2lds16(const void* g, void* l){
  __builtin_amdgcn_global_load_lds((const __attribute__((address_space(1))) unsigned int*)g,
                                   (__attribute__((address_space(3))) unsigned int*)l, 16, 0, 0);
}

// fp8 e4m3 helpers (HW cvt, gfx940+)
__device__ __forceinline__ unsigned char f2fp8(float v){
  int r = __builtin_amdgcn_cvt_pk_fp8_f32(v, v, 0, false);
  return (unsigned char)(r & 0xff);
}
__device__ __forceinline__ void dec8(const unsigned char* p, float* o){
  uint2 d = *reinterpret_cast<const uint2*>(p);
  f32x2 a = __builtin_amdgcn_cvt_pk_f32_fp8(d.x, false);
  f32x2 b = __builtin_amdgcn_cvt_pk_f32_fp8(d.x, true);
  f32x2 c = __builtin_amdgcn_cvt_pk_f32_fp8(d.y, false);
  f32x2 e = __builtin_amdgcn_cvt_pk_f32_fp8(d.y, true);
  o[0]=a.x; o[1]=a.y; o[2]=b.x; o[3]=b.y; o[4]=c.x; o[5]=c.y; o[6]=e.x; o[7]=e.y;
}

// ---------------- fused count + prep ----------------
#define EB 3125                                    // ceil(N_EDGES/256)
#define XCVT_N (N_NODES*NODE_DIMC/4)
#define EMBWT_N (NODE_DIMC*HDIM)
#define GCNWT_N (NLAYERS*HDIM*HDIM)
#define BN_N (NLAYERS*HDIM)
#define PREP_TOTAL (XCVT_N + EMBWT_N + GCNWT_N + BN_N)
#define PREP_BLKS ((PREP_TOTAL + 255)/256)

__global__ void k_countprep(const int* __restrict__ ei, int* __restrict__ cnt,
                            const float* __restrict__ x, unsigned short* __restrict__ xb,
                            const float* __restrict__ embW, unsigned short* __restrict__ embWt,
                            const float* __restrict__ gcnW, unsigned short* __restrict__ gcnWt,
                            const float* __restrict__ gcnb, const float* __restrict__ bng,
                            const float* __restrict__ bnb, const float* __restrict__ bnm,
                            const float* __restrict__ bnv, float* __restrict__ S, float* __restrict__ T){
  int b = blockIdx.x;
  if (b < EB){
    int e = b*256 + threadIdx.x;
    if (e < N_EDGES) atomicAdd(&cnt[ei[N_EDGES + e]], 1);
    return;
  }
  int idx = (b - EB)*256 + threadIdx.x;
  if (idx < XCVT_N){
    float4 v = ld4(x + (size_t)idx*4);
    ushort4 o;
    o.x = f2bf(v.x); o.y = f2bf(v.y); o.z = f2bf(v.z); o.w = f2bf(v.w);
    *reinterpret_cast<ushort4*>(xb + (size_t)idx*4) = o;
    return;
  }
  idx -= XCVT_N;
  if (idx < EMBWT_N){
    int c = idx >> 7, k = idx & 127;
    embWt[idx] = f2bf(embW[(size_t)k*HDIM + c]);
    return;
  }
  idx -= EMBWT_N;
  if (idx < GCNWT_N){
    int l = idx >> 16, rem = idx & 65535;
    int c = rem >> 8, k = rem & 255;
    gcnWt[idx] = f2bf(gcnW[(size_t)l*HDIM*HDIM + (size_t)k*HDIM + c]);
    return;
  }
  idx -= GCNWT_N;
  if (idx < BN_N){
    float s = bng[idx] * rsqrtf(bnv[idx] + BN_EPSF);
    S[idx] = s;
    T[idx] = (gcnb[idx] - bnm[idx]) * s + bnb[idx];
  }
}

// ---------------- scans ----------------
__global__ void k_scan1(const int* __restrict__ cnt, int* __restrict__ rowp, int* __restrict__ part){
  __shared__ int s[256];
  int t = threadIdx.x;
  int i = blockIdx.x*256 + t;
  int v = (i < N_NODES) ? cnt[i] : 0;
  s[t] = v;
  __syncthreads();
  #pragma unroll
  for (int off=1; off<256; off<<=1){
    int x = s[t];
    int y = (t >= off) ? s[t-off] : 0;
    __syncthreads();
    s[t] = x + y;
    __syncthreads();
  }
  if (i < N_NODES) rowp[i+1] = s[t];
  if (t == 255) part[blockIdx.x] = s[255];
}

__global__ void k_scan2(int* __restrict__ part){
  __shared__ int s[256];
  int t = threadIdx.x;
  int v = (t < NBLK) ? part[t] : 0;
  s[t] = v;
  __syncthreads();
  #pragma unroll
  for (int off=1; off<256; off<<=1){
    int x = s[t];
    int y = (t >= off) ? s[t-off] : 0;
    __syncthreads();
    s[t] = x + y;
    __syncthreads();
  }
  if (t < NBLK) part[t] = s[t] - v;   // exclusive offsets
}

__global__ void k_scan3(const int* __restrict__ cnt, int* __restrict__ rowp,
                        const int* __restrict__ part, float* __restrict__ dinv){
  int i = blockIdx.x*256 + threadIdx.x;
  if (i < N_NODES){
    rowp[i+1] += part[blockIdx.x];
    dinv[i] = rsqrtf(1.0f + (float)cnt[i]);
  }
  if (i == 0) rowp[0] = 0;
}

// slot claim via atomicSub on cnt (cnt dead after this kernel; re-built every call)
__global__ void k_fill(const int* __restrict__ ei, const int* __restrict__ rowp, int* __restrict__ cnt,
                       const float* __restrict__ dinv, int2* __restrict__ csr){
  int e = blockIdx.x*256 + threadIdx.x;
  if (e >= N_EDGES) return;
  int sr = ei[e];
  int ds = ei[N_EDGES + e];
  int pos = rowp[ds] + atomicSub(&cnt[ds], 1) - 1;
  csr[pos] = make_int2(sr, __float_as_int(dinv[sr]));
}

// ---------------- bf16 MFMA GEMM: BM=64 x BN=256 (full width), BK=32, dbuf LDS ----------------
// EMB=true: bias+relu -> bf16 h. EMB=false: -> fp8 e4m3 m8[node][256].
template<int K, bool EMB>
__global__ __launch_bounds__(256) void k_mgemm(const unsigned short* __restrict__ A,
                                               const unsigned short* __restrict__ Wt,
                                               const float* __restrict__ bias,
                                               unsigned short* __restrict__ outp,
                                               unsigned char* __restrict__ outp8,
                                               int nrows){
  __shared__ unsigned short SMEM[20480];   // 40,960 B
  unsigned short* As0 = SMEM;              // As[buf] = SMEM + buf*2048 (64 rows x 32 k)
  unsigned short* Bs0 = SMEM + 4096;       // Bs[buf] = SMEM + 4096 + buf*8192 (256 cols x 32 k)
  const int t = threadIdx.x;
  const int lane = t & 63;
  const int wid = t >> 6;
  const int row0 = blockIdx.x * 64;
  constexpr int NK = K / 32;

  f32x4 acc[4][4];
  #pragma unroll
  for (int i=0;i<4;i++)
    #pragma unroll
    for (int j=0;j<4;j++) acc[i][j] = (f32x4){0.f,0.f,0.f,0.f};

  auto stage = [&](int buf, int k0){
    {
      int c0 = wid*64;
      int c  = c0 + lane;
      int cs = c ^ ((c >> 3) & 7);
      int r  = cs >> 2;
      int kp = (cs & 3) * 8;
      gl2lds16(A + (size_t)(row0 + r)*K + k0 + kp, As0 + buf*2048 + c0*8);
    }
    #pragma unroll
    for (int i=0;i<4;i++){
      int c0 = (wid*4 + i)*64;
      int c  = c0 + lane;
      int cs = c ^ ((c >> 3) & 7);
      int col = cs >> 2;
      int kp  = (cs & 3) * 8;
      gl2lds16(Wt + (size_t)col*K + k0 + kp, Bs0 + buf*8192 + c0*8);
    }
  };

  stage(0, 0);
  int cur = 0;
  #pragma unroll
  for (int tk = 0; tk < NK; ++tk){
    if (tk + 1 < NK){
      stage(cur ^ 1, (tk+1)*32);
      asm volatile("s_waitcnt vmcnt(5)" ::: "memory");
    } else {
      asm volatile("s_waitcnt vmcnt(0)" ::: "memory");
    }
    __builtin_amdgcn_s_barrier();
    const int kofs = (lane >> 4) * 8;
    short8 af[4], bfv[4];
    #pragma unroll
    for (int mi=0;mi<4;mi++){
      int r = mi*16 + (lane & 15);
      int idx = r*32 + kofs;
      int sw = idx ^ (((idx >> 6) & 7) << 3);
      af[mi] = *reinterpret_cast<const short8*>(As0 + cur*2048 + sw);
    }
    #pragma unroll
    for (int ni=0;ni<4;ni++){
      int col = wid*64 + ni*16 + (lane & 15);
      int idx = col*32 + kofs;
      int sw = idx ^ (((idx >> 6) & 7) << 3);
      bfv[ni] = *reinterpret_cast<const short8*>(Bs0 + cur*8192 + sw);
    }
    #pragma unroll
    for (int mi=0;mi<4;mi++)
      #pragma unroll
      for (int ni=0;ni<4;ni++)
        acc[mi][ni] = __builtin_amdgcn_mfma_f32_16x16x32_bf16(af[mi], bfv[ni], acc[mi][ni], 0, 0, 0);
    __builtin_amdgcn_s_barrier();
    cur ^= 1;
  }

  __syncthreads();   // all waves done with As/Bs before SMEM reuse
  if constexpr (EMB){
    // acc -> CT[64][268] bf16 -> coalesced u16x8 stores
    unsigned short* CT = SMEM;
    #pragma unroll
    for (int mi=0;mi<4;mi++){
      #pragma unroll
      for (int j=0;j<4;j++){
        int rl = mi*16 + (lane >> 4)*4 + j;
        #pragma unroll
        for (int ni=0;ni<4;ni++){
          float v = acc[mi][ni][j];
          int cl = wid*64 + ni*16 + (lane & 15);
          v = fmaxf(v + bias[cl], 0.f);
          CT[rl*268 + cl] = f2bf(v);
        }
      }
    }
    __syncthreads();
    #pragma unroll
    for (int it=0; it<8; ++it){
      int cidx = t + it*256;
      int rl = cidx >> 5;
      int ck = cidx & 31;
      int gr = row0 + rl;
      if (gr < nrows){
        u16x8 v = *reinterpret_cast<const u16x8*>(CT + rl*268 + ck*8);
        *reinterpret_cast<u16x8*>(outp + (size_t)gr*HDIM + ck*8) = v;
      }
    }
  } else {
    // acc -> CT8[64][272] fp8 -> coalesced 16B stores
    unsigned char* CT8 = reinterpret_cast<unsigned char*>(SMEM);
    #pragma unroll
    for (int mi=0;mi<4;mi++){
      #pragma unroll
      for (int j=0;j<4;j++){
        int rl = mi*16 + (lane >> 4)*4 + j;
        #pragma unroll
        for (int ni=0;ni<4;ni++){
          int cl = wid*64 + ni*16 + (lane & 15);
          CT8[rl*272 + cl] = f2fp8(acc[mi][ni][j]);
        }
      }
    }
    __syncthreads();
    #pragma unroll
    for (int it=0; it<4; ++it){
      int cidx = t + it*256;          // 0..1023 (64 rows x 16 chunks of 16B)
      int rl = cidx >> 4;
      int ck = cidx & 15;
      int gr = row0 + rl;
      if (gr < nrows){
        uint4 v = *reinterpret_cast<const uint4*>(CT8 + rl*272 + ck*16);
        *reinterpret_cast<uint4*>(outp8 + (size_t)gr*HDIM + ck*16) = v;
      }
    }
  }
}

// ---------------- fused aggregation: half-wave edge split, 4-deep, fp8 m gather, bf16 h ----------------
__global__ __launch_bounds__(256) void k_agg(const unsigned char* __restrict__ m8, const int* __restrict__ rowp,
                                             const int2* __restrict__ csr,
                                             const float* __restrict__ S, const float* __restrict__ T,
                                             unsigned short* __restrict__ h){
  int node = blockIdx.x*4 + (threadIdx.x >> 6);
  int lane = threadIdx.x & 63;
  int half = lane >> 5;
  int c = (lane & 31) * 8;

  int s = rowp[node], e = rowp[node+1];
  float dn = rsqrtf(1.0f + (float)(e - s));   // deg = 1 + in-degree

  float acc[8];
  if (half == 0){
    float ms[8];
    dec8(m8 + (size_t)node*HDIM + c, ms);
    #pragma unroll
    for (int j=0;j<8;j++) acc[j] = ms[j] * dn;
  } else {
    #pragma unroll
    for (int j=0;j<8;j++) acc[j] = 0.f;
  }

  int i = s + half;
  for (; i + 6 < e; i += 8){
    int2 e0 = csr[i], e1 = csr[i+2], e2 = csr[i+4], e3 = csr[i+6];
    float w0 = __int_as_float(e0.y), w1 = __int_as_float(e1.y);
    float w2 = __int_as_float(e2.y), w3 = __int_as_float(e3.y);
    float f0[8], f1[8], f2[8], f3[8];
    dec8(m8 + (size_t)e0.x*HDIM + c, f0);
    dec8(m8 + (size_t)e1.x*HDIM + c, f1);
    dec8(m8 + (size_t)e2.x*HDIM + c, f2);
    dec8(m8 + (size_t)e3.x*HDIM + c, f3);
    #pragma unroll
    for (int j=0;j<8;j++){
      acc[j] += w0*f0[j] + w1*f1[j];
      acc[j] += w2*f2[j] + w3*f3[j];
    }
  }
  if (i + 2 < e){
    int2 e0 = csr[i], e1 = csr[i+2];
    float w0 = __int_as_float(e0.y), w1 = __int_as_float(e1.y);
    float f0[8], f1[8];
    dec8(m8 + (size_t)e0.x*HDIM + c, f0);
    dec8(m8 + (size_t)e1.x*HDIM + c, f1);
    #pragma unroll
    for (int j=0;j<8;j++) acc[j] += w0*f0[j] + w1*f1[j];
    i += 4;
  }
  if (i < e){
    int2 e0 = csr[i];
    float w0 = __int_as_float(e0.y);
    float f0[8];
    dec8(m8 + (size_t)e0.x*HDIM + c, f0);
    #pragma unroll
    for (int j=0;j<8;j++) acc[j] += w0*f0[j];
  }

  #pragma unroll
  for (int j=0;j<8;j++) acc[j] += __shfl_xor(acc[j], 32);

  if (half == 0){
    const size_t base = (size_t)node*HDIM + c;
    float4 S0 = ld4(S + c), S1 = ld4(S + c + 4);
    float4 T0 = ld4(T + c), T1 = ld4(T + c + 4);
    u16x8 hold = *reinterpret_cast<const u16x8*>(h + base);
    float Sv[8] = {S0.x,S0.y,S0.z,S0.w,S1.x,S1.y,S1.z,S1.w};
    float Tv[8] = {T0.x,T0.y,T0.z,T0.w,T1.x,T1.y,T1.z,T1.w};
    u16x8 ob;
    #pragma unroll
    for (int j=0;j<8;j++){
      float o = fmaxf(acc[j]*dn*Sv[j] + Tv[j], 0.f) + bf2f(hold[j]);
      ob[j] = f2bf(o);
    }
    *reinterpret_cast<u16x8*>(h + base) = ob;
  }
}

// ---------------- global mean pool (batch_idx sorted), bf16 h ----------------
__device__ __forceinline__ int lbound(const int* __restrict__ a, int n, int key){
  int lo = 0, hi = n;
  while (lo < hi){ int mid = (lo + hi) >> 1; if (a[mid] < key) lo = mid + 1; else hi = mid; }
  return lo;
}

__global__ __launch_bounds__(128) void k_pool(const unsigned short* __restrict__ h, const int* __restrict__ batch,
                                              float* __restrict__ g){
  int gi = blockIdx.x;
  int lo = lbound(batch, N_NODES, gi);
  int hi = lbound(batch, N_NODES, gi + 1);
  int t = threadIdx.x;
  float s0 = 0.f, s1 = 0.f;
  for (int n = lo; n < hi; ++n){
    unsigned u = *reinterpret_cast<const unsigned*>(h + (size_t)n*HDIM + 2*t);
    s0 += bf2f((unsigned short)(u & 0xffffu));
    s1 += bf2f((unsigned short)(u >> 16));
  }
  float inv = 1.0f / fmaxf((float)(hi - lo), 1.0f);
  g[(size_t)gi*HDIM + 2*t]     = s0 * inv;
  g[(size_t)gi*HDIM + 2*t + 1] = s1 * inv;
}

// ---------------- fused 3-layer property heads, GB graphs per block ----------------
__global__ __launch_bounds__(128) void k_heads(const float* __restrict__ g,
                                               const float* __restrict__ W1, const float* __restrict__ b1,
                                               const float* __restrict__ W2, const float* __restrict__ b2,
                                               const float* __restrict__ W3, const float* __restrict__ b3,
                                               float* __restrict__ out){
  int g0 = blockIdx.x * GB, p = blockIdx.y;
  __shared__ float gs[GB][HDIM];
  __shared__ float z1[GB][128];
  int t = threadIdx.x;
  #pragma unroll
  for (int gi=0; gi<GB; gi++){
    gs[gi][t]       = g[(size_t)(g0+gi)*HDIM + t];
    gs[gi][t + 128] = g[(size_t)(g0+gi)*HDIM + t + 128];
  }
  __syncthreads();

  const float* w1 = W1 + (size_t)p*HDIM*128;
  float a[GB];
  #pragma unroll
  for (int gi=0; gi<GB; gi++) a[gi] = 0.f;
  for (int i=0;i<HDIM;i++){
    float wv = w1[(size_t)i*128 + t];
    #pragma unroll
    for (int gi=0; gi<GB; gi++) a[gi] += gs[gi][i] * wv;
  }
  float b1v = b1[p*128 + t];
  #pragma unroll
  for (int gi=0; gi<GB; gi++) z1[gi][t] = fmaxf(a[gi] + b1v, 0.f);
  __syncthreads();

  if (t < 64){
    const float* w2 = W2 + (size_t)p*128*64;
    float a2[GB];
    #pragma unroll
    for (int gi=0; gi<GB; gi++) a2[gi] = 0.f;
    for (int i=0;i<128;i++){
      float wv = w2[(size_t)i*64 + t];
      #pragma unroll
      for (int gi=0; gi<GB; gi++) a2[gi] += z1[gi][i] * wv;
    }
    float w3v = W3[p*64 + t];
    float b2v = b2[p*64 + t];
    float b3v = b3[p];
    #pragma unroll
    for (int gi=0; gi<GB; gi++){
      float z2 = fmaxf(a2[gi] + b2v, 0.f);
      float v = z2 * w3v;
      #pragma unroll
      for (int off=32; off>0; off>>=1) v += __shfl_down(v, off, 64);
      if (t == 0) out[(size_t)(g0+gi)*NPROPS + p] = v + b3v;
    }
  }
}

// ---------------- launch ----------------
extern "C" void kernel_launch(void* const* d_in, const int* in_sizes, int n_in,
                              void* d_out, int out_size, void* d_ws, size_t ws_size,
                              hipStream_t stream){
  const float* x     = (const float*)d_in[0];
  const int*   ei    = (const int*)  d_in[1];
  const int*   batch = (const int*)  d_in[2];
  const float* embW  = (const float*)d_in[3];
  const float* embb  = (const float*)d_in[4];
  const float* gcnW  = (const float*)d_in[5];
  const float* gcnb  = (const float*)d_in[6];
  const float* bng   = (const float*)d_in[7];
  const float* bnb   = (const float*)d_in[8];
  const float* bnm   = (const float*)d_in[9];
  const float* bnv   = (const float*)d_in[10];
  const float* h1W   = (const float*)d_in[11];
  const float* h1b   = (const float*)d_in[12];
  const float* h2W   = (const float*)d_in[13];
  const float* h2b   = (const float*)d_in[14];
  const float* h3W   = (const float*)d_in[15];
  const float* h3b   = (const float*)d_in[16];
  float* out = (float*)d_out;

  char* w = (char*)d_ws;
  auto alloc = [&](size_t bytes)->char*{ char* p = w; w += (bytes + 255) & ~(size_t)255; return p; };
  unsigned short* h    = (unsigned short*)alloc((size_t)N_NODES*HDIM*2);   // bf16 h
  char*           mbuf =                  alloc((size_t)N_NODES*HDIM);     // 12.8MB: xb (bf16, pre-emb) then m8 (fp8)
  int*   cnt  = (int*)  alloc((size_t)N_NODES*4);
  int*   rowp = (int*)  alloc((size_t)(N_NODES+1)*4);
  float* dinv = (float*)alloc((size_t)N_NODES*4);
  int2*  csr  = (int2*) alloc((size_t)N_EDGES*8);
  int*   part = (int*)  alloc(1024);
  float* gp   = (float*)alloc((size_t)N_GRAPHS*HDIM*4);
  unsigned short* embWt = (unsigned short*)alloc((size_t)NODE_DIMC*HDIM*2);
  unsigned short* gcnWt = (unsigned short*)alloc((size_t)NLAYERS*HDIM*HDIM*2);
  float* bnS  = (float*)alloc((size_t)NLAYERS*HDIM*4);
  float* bnT  = (float*)alloc((size_t)NLAYERS*HDIM*4);

  unsigned short* xb = (unsigned short*)mbuf;   // N x 128 bf16 = 12.8MB (dead after emb GEMM)
  unsigned char*  m8 = (unsigned char*)mbuf;    // N x 256 fp8  = 12.8MB

  hipMemsetAsync(cnt, 0, (size_t)N_NODES*4, stream);

  k_countprep<<<EB + PREP_BLKS,256,0,stream>>>(ei, cnt, x, xb, embW, embWt, gcnW, gcnWt,
                                               gcnb, bng, bnb, bnm, bnv, bnS, bnT);
  k_scan1<<<NBLK,256,0,stream>>>(cnt, rowp, part);
  k_scan2<<<1,256,0,stream>>>(part);
  k_scan3<<<NBLK,256,0,stream>>>(cnt, rowp, part, dinv);
  k_fill<<<EB,256,0,stream>>>(ei, rowp, cnt, dinv, csr);

  const int RB64 = (N_NODES + 63)/64;   // 782 blocks, full-width tiles
  k_mgemm<NODE_DIMC, true><<<RB64,256,0,stream>>>(xb, embWt, embb, h, nullptr, N_NODES);

  for (int l = 0; l < NLAYERS; ++l){
    k_mgemm<HDIM, false><<<RB64,256,0,stream>>>(h, gcnWt + (size_t)l*HDIM*HDIM, nullptr, nullptr, m8, N_NODES);
    k_agg<<<(N_NODES+3)/4,256,0,stream>>>(m8, rowp, csr, bnS + l*HDIM, bnT + l*HDIM, h);
  }

  k_pool<<<N_GRAPHS,128,0,stream>>>(h, batch, gp);
  k_heads<<<dim3((N_GRAPHS+GB-1)/GB,NPROPS),128,0,stream>>>(gp, h1W, h1b, h2W, h2b, h3W, h3b, out);
}

// Round 15
// 330.706 us; speedup vs baseline: 1.8012x; 1.1625x over previous
//
#include <hip/hip_runtime.h>

#define N_NODES 50000
#define N_EDGES 800000
#define N_GRAPHS 1000
#define NODE_DIMC 128
#define HDIM 256
#define NLAYERS 4
#define NPROPS 3
#define BN_EPSF 1e-5f
#define GB 8        // graphs per head-block
#define NBKT 196    // dst>>8 buckets (max ds 49999 -> 195)
#define BCAP 5120   // bucket capacity (mean 4096, std ~64 -> 16 sigma)
#define EPB 4096    // edges per pass-A block

typedef __attribute__((ext_vector_type(4))) float f32x4;
typedef __attribute__((ext_vector_type(2))) float f32x2;
typedef __attribute__((ext_vector_type(8))) short short8;
typedef __attribute__((ext_vector_type(8))) unsigned short u16x8;

__device__ __forceinline__ float4 ld4(const float* p){ return *reinterpret_cast<const float4*>(p); }
__device__ __forceinline__ unsigned short f2bf(float f){
  unsigned u = __float_as_uint(f);
  return (unsigned short)((u + 0x7FFFu + ((u >> 16) & 1u)) >> 16);
}
__device__ __forceinline__ float bf2f(unsigned short s){ return __uint_as_float(((unsigned)s) << 16); }

__device__ __forceinline__ void gl2lds16(const void* g, void* l){
  __builtin_amdgcn_global_load_lds((const __attribute__((address_space(1))) unsigned int*)g,
                                   (__attribute__((address_space(3))) unsigned int*)l, 16, 0, 0);
}

// fp8 e4m3 helpers (HW cvt)
__device__ __forceinline__ unsigned char f2fp8(float v){
  int r = __builtin_amdgcn_cvt_pk_fp8_f32(v, v, 0, false);
  return (unsigned char)(r & 0xff);
}
__device__ __forceinline__ void dec8(const unsigned char* p, float* o){
  uint2 d = *reinterpret_cast<const uint2*>(p);
  f32x2 a = __builtin_amdgcn_cvt_pk_f32_fp8(d.x, false);
  f32x2 b = __builtin_amdgcn_cvt_pk_f32_fp8(d.x, true);
  f32x2 c = __builtin_amdgcn_cvt_pk_f32_fp8(d.y, false);
  f32x2 e = __builtin_amdgcn_cvt_pk_f32_fp8(d.y, true);
  o[0]=a.x; o[1]=a.y; o[2]=b.x; o[3]=b.y; o[4]=c.x; o[5]=c.y; o[6]=e.x; o[7]=e.y;
}

// ---------------- Pass A: bucket-scatter edges + prep (fused) ----------------
#define XCVT_N (N_NODES*NODE_DIMC/4)
#define EMBWT_N (NODE_DIMC*HDIM)
#define GCNWT_N (NLAYERS*HDIM*HDIM)
#define BN_N (NLAYERS*HDIM)
#define PREP_TOTAL (XCVT_N + EMBWT_N + GCNWT_N + BN_N)
#define PREP_BLKS ((PREP_TOTAL + 255)/256)

__global__ __launch_bounds__(256) void k_bucketprep(const int* __restrict__ ei, int* __restrict__ bktsz,
                            unsigned* __restrict__ bkt,
                            const float* __restrict__ x, unsigned short* __restrict__ xb,
                            const float* __restrict__ embW, unsigned short* __restrict__ embWt,
                            const float* __restrict__ gcnW, unsigned short* __restrict__ gcnWt,
                            const float* __restrict__ gcnb, const float* __restrict__ bng,
                            const float* __restrict__ bnb, const float* __restrict__ bnm,
                            const float* __restrict__ bnv, float* __restrict__ S, float* __restrict__ T){
  int b = blockIdx.x;
  int t = threadIdx.x;
  if (b < (N_EDGES + EPB - 1)/EPB){
    __shared__ int hist[NBKT];
    __shared__ int gbase[NBKT];
    __shared__ int cur[NBKT];
    if (t < NBKT){ hist[t] = 0; cur[t] = 0; }
    __syncthreads();
    int e0 = b*EPB;
    for (int i = t; i < EPB; i += 256){
      int e = e0 + i;
      if (e < N_EDGES) atomicAdd(&hist[ei[N_EDGES + e] >> 8], 1);
    }
    __syncthreads();
    if (t < NBKT) gbase[t] = (hist[t] > 0) ? atomicAdd(&bktsz[t], hist[t]) : 0;
    __syncthreads();
    for (int i = t; i < EPB; i += 256){
      int e = e0 + i;
      if (e < N_EDGES){
        int sr = ei[e];
        int ds = ei[N_EDGES + e];
        int bb = ds >> 8;
        int pos = gbase[bb] + atomicAdd(&cur[bb], 1);
        if (pos < BCAP) bkt[(size_t)bb*BCAP + pos] = ((unsigned)ds << 16) | (unsigned)sr;
      }
    }
    return;
  }
  int idx = (b - (N_EDGES + EPB - 1)/EPB)*256 + t;
  if (idx < XCVT_N){
    float4 v = ld4(x + (size_t)idx*4);
    ushort4 o;
    o.x = f2bf(v.x); o.y = f2bf(v.y); o.z = f2bf(v.z); o.w = f2bf(v.w);
    *reinterpret_cast<ushort4*>(xb + (size_t)idx*4) = o;
    return;
  }
  idx -= XCVT_N;
  if (idx < EMBWT_N){
    int c = idx >> 7, k = idx & 127;
    embWt[idx] = f2bf(embW[(size_t)k*HDIM + c]);
    return;
  }
  idx -= EMBWT_N;
  if (idx < GCNWT_N){
    int l = idx >> 16, rem = idx & 65535;
    int c = rem >> 8, k = rem & 255;
    gcnWt[idx] = f2bf(gcnW[(size_t)l*HDIM*HDIM + (size_t)k*HDIM + c]);
    return;
  }
  idx -= GCNWT_N;
  if (idx < BN_N){
    float s = bng[idx] * rsqrtf(bnv[idx] + BN_EPSF);
    S[idx] = s;
    T[idx] = (gcnb[idx] - bnm[idx]) * s + bnb[idx];
  }
}

// ---------------- bucket-size scan ----------------
__global__ void k_bscan(const int* __restrict__ bktsz, int* __restrict__ bktbase, int* __restrict__ rowp){
  __shared__ int s[256];
  int t = threadIdx.x;
  int v = (t < NBKT) ? bktsz[t] : 0;
  s[t] = v;
  __syncthreads();
  #pragma unroll
  for (int off=1; off<256; off<<=1){
    int x = s[t];
    int y = (t >= off) ? s[t-off] : 0;
    __syncthreads();
    s[t] = x + y;
    __syncthreads();
  }
  if (t < NBKT) bktbase[t] = s[t] - v;   // exclusive
  if (t == 0) rowp[N_NODES] = N_EDGES;
}

// ---------------- Pass B: per-bucket count/scan/fill -> rowp, dinv, csrs ----------------
__global__ __launch_bounds__(256) void k_bfill(const unsigned* __restrict__ bkt, const int* __restrict__ bktsz,
                       const int* __restrict__ bktbase,
                       int* __restrict__ rowp, float* __restrict__ dinv, int* __restrict__ csrs){
  int b = blockIdx.x;
  int t = threadIdx.x;
  __shared__ int cnt[256];
  __shared__ int off[256];
  __shared__ int cur[256];
  __shared__ int sc[256];
  cnt[t] = 0; cur[t] = 0;
  __syncthreads();
  int n = min(bktsz[b], BCAP);
  int base = bktbase[b];
  const unsigned* mybkt = bkt + (size_t)b*BCAP;
  for (int i = t; i < n; i += 256)
    atomicAdd(&cnt[(mybkt[i] >> 16) & 255], 1);
  __syncthreads();
  sc[t] = cnt[t];
  __syncthreads();
  #pragma unroll
  for (int o=1; o<256; o<<=1){
    int x = sc[t];
    int y = (t >= o) ? sc[t-o] : 0;
    __syncthreads();
    sc[t] = x + y;
    __syncthreads();
  }
  off[t] = sc[t] - cnt[t];
  int node = b*256 + t;
  if (node < N_NODES){
    rowp[node] = base + off[t];
    dinv[node] = rsqrtf(1.0f + (float)cnt[t]);
  }
  __syncthreads();
  for (int i = t; i < n; i += 256){
    unsigned e = mybkt[i];
    int local = (e >> 16) & 255;
    int pos = base + off[local] + atomicAdd(&cur[local], 1);
    csrs[pos] = (int)(e & 0xffffu);
  }
}

// ---------------- bf16 MFMA GEMM: BM=64 x BN=256 (full width), BK=32, dbuf LDS ----------------
// EMB=true: bias+relu -> bf16 h. EMB=false: -> fp8 e4m3 m8[node][256].
template<int K, bool EMB>
__global__ __launch_bounds__(256) void k_mgemm(const unsigned short* __restrict__ A,
                                               const unsigned short* __restrict__ Wt,
                                               const float* __restrict__ bias,
                                               unsigned short* __restrict__ outp,
                                               unsigned char* __restrict__ outp8,
                                               int nrows){
  __shared__ unsigned short SMEM[20480];   // 40,960 B
  unsigned short* As0 = SMEM;
  unsigned short* Bs0 = SMEM + 4096;
  const int t = threadIdx.x;
  const int lane = t & 63;
  const int wid = t >> 6;
  const int row0 = blockIdx.x * 64;
  constexpr int NK = K / 32;

  f32x4 acc[4][4];
  #pragma unroll
  for (int i=0;i<4;i++)
    #pragma unroll
    for (int j=0;j<4;j++) acc[i][j] = (f32x4){0.f,0.f,0.f,0.f};

  auto stage = [&](int buf, int k0){
    {
      int c0 = wid*64;
      int c  = c0 + lane;
      int cs = c ^ ((c >> 3) & 7);
      int r  = cs >> 2;
      int kp = (cs & 3) * 8;
      gl2lds16(A + (size_t)(row0 + r)*K + k0 + kp, As0 + buf*2048 + c0*8);
    }
    #pragma unroll
    for (int i=0;i<4;i++){
      int c0 = (wid*4 + i)*64;
      int c  = c0 + lane;
      int cs = c ^ ((c >> 3) & 7);
      int col = cs >> 2;
      int kp  = (cs & 3) * 8;
      gl2lds16(Wt + (size_t)col*K + k0 + kp, Bs0 + buf*8192 + c0*8);
    }
  };

  stage(0, 0);
  int cur = 0;
  #pragma unroll
  for (int tk = 0; tk < NK; ++tk){
    if (tk + 1 < NK){
      stage(cur ^ 1, (tk+1)*32);
      asm volatile("s_waitcnt vmcnt(5)" ::: "memory");
    } else {
      asm volatile("s_waitcnt vmcnt(0)" ::: "memory");
    }
    __builtin_amdgcn_s_barrier();
    const int kofs = (lane >> 4) * 8;
    short8 af[4], bfv[4];
    #pragma unroll
    for (int mi=0;mi<4;mi++){
      int r = mi*16 + (lane & 15);
      int idx = r*32 + kofs;
      int sw = idx ^ (((idx >> 6) & 7) << 3);
      af[mi] = *reinterpret_cast<const short8*>(As0 + cur*2048 + sw);
    }
    #pragma unroll
    for (int ni=0;ni<4;ni++){
      int col = wid*64 + ni*16 + (lane & 15);
      int idx = col*32 + kofs;
      int sw = idx ^ (((idx >> 6) & 7) << 3);
      bfv[ni] = *reinterpret_cast<const short8*>(Bs0 + cur*8192 + sw);
    }
    #pragma unroll
    for (int mi=0;mi<4;mi++)
      #pragma unroll
      for (int ni=0;ni<4;ni++)
        acc[mi][ni] = __builtin_amdgcn_mfma_f32_16x16x32_bf16(af[mi], bfv[ni], acc[mi][ni], 0, 0, 0);
    __builtin_amdgcn_s_barrier();
    cur ^= 1;
  }

  __syncthreads();
  if constexpr (EMB){
    unsigned short* CT = SMEM;
    #pragma unroll
    for (int mi=0;mi<4;mi++){
      #pragma unroll
      for (int j=0;j<4;j++){
        int rl = mi*16 + (lane >> 4)*4 + j;
        #pragma unroll
        for (int ni=0;ni<4;ni++){
          float v = acc[mi][ni][j];
          int cl = wid*64 + ni*16 + (lane & 15);
          v = fmaxf(v + bias[cl], 0.f);
          CT[rl*268 + cl] = f2bf(v);
        }
      }
    }
    __syncthreads();
    #pragma unroll
    for (int it=0; it<8; ++it){
      int cidx = t + it*256;
      int rl = cidx >> 5;
      int ck = cidx & 31;
      int gr = row0 + rl;
      if (gr < nrows){
        u16x8 v = *reinterpret_cast<const u16x8*>(CT + rl*268 + ck*8);
        *reinterpret_cast<u16x8*>(outp + (size_t)gr*HDIM + ck*8) = v;
      }
    }
  } else {
    unsigned char* CT8 = reinterpret_cast<unsigned char*>(SMEM);
    #pragma unroll
    for (int mi=0;mi<4;mi++){
      #pragma unroll
      for (int j=0;j<4;j++){
        int rl = mi*16 + (lane >> 4)*4 + j;
        #pragma unroll
        for (int ni=0;ni<4;ni++){
          int cl = wid*64 + ni*16 + (lane & 15);
          CT8[rl*272 + cl] = f2fp8(acc[mi][ni][j]);
        }
      }
    }
    __syncthreads();
    #pragma unroll
    for (int it=0; it<4; ++it){
      int cidx = t + it*256;
      int rl = cidx >> 4;
      int ck = cidx & 15;
      int gr = row0 + rl;
      if (gr < nrows){
        uint4 v = *reinterpret_cast<const uint4*>(CT8 + rl*272 + ck*16);
        *reinterpret_cast<uint4*>(outp8 + (size_t)gr*HDIM + ck*16) = v;
      }
    }
  }
}

// ---------------- fused aggregation: half-wave edge split, 4-deep, fp8 m gather, bf16 h ----------------
__global__ __launch_bounds__(256) void k_agg(const unsigned char* __restrict__ m8, const int* __restrict__ rowp,
                                             const int* __restrict__ csrs, const float* __restrict__ dinv,
                                             const float* __restrict__ S, const float* __restrict__ T,
                                             unsigned short* __restrict__ h){
  int node = blockIdx.x*4 + (threadIdx.x >> 6);
  int lane = threadIdx.x & 63;
  int half = lane >> 5;
  int c = (lane & 31) * 8;

  int s = rowp[node], e = rowp[node+1];
  float dn = rsqrtf(1.0f + (float)(e - s));   // deg = 1 + in-degree

  float acc[8];
  if (half == 0){
    float ms[8];
    dec8(m8 + (size_t)node*HDIM + c, ms);
    #pragma unroll
    for (int j=0;j<8;j++) acc[j] = ms[j] * dn;
  } else {
    #pragma unroll
    for (int j=0;j<8;j++) acc[j] = 0.f;
  }

  int i = s + half;
  for (; i + 6 < e; i += 8){
    int s0 = csrs[i], s1 = csrs[i+2], s2 = csrs[i+4], s3 = csrs[i+6];
    float w0 = dinv[s0], w1 = dinv[s1], w2 = dinv[s2], w3 = dinv[s3];
    float f0[8], f1[8], f2[8], f3[8];
    dec8(m8 + (size_t)s0*HDIM + c, f0);
    dec8(m8 + (size_t)s1*HDIM + c, f1);
    dec8(m8 + (size_t)s2*HDIM + c, f2);
    dec8(m8 + (size_t)s3*HDIM + c, f3);
    #pragma unroll
    for (int j=0;j<8;j++){
      acc[j] += w0*f0[j] + w1*f1[j];
      acc[j] += w2*f2[j] + w3*f3[j];
    }
  }
  if (i + 2 < e){
    int s0 = csrs[i], s1 = csrs[i+2];
    float w0 = dinv[s0], w1 = dinv[s1];
    float f0[8], f1[8];
    dec8(m8 + (size_t)s0*HDIM + c, f0);
    dec8(m8 + (size_t)s1*HDIM + c, f1);
    #pragma unroll
    for (int j=0;j<8;j++) acc[j] += w0*f0[j] + w1*f1[j];
    i += 4;
  }
  if (i < e){
    int s0 = csrs[i];
    float w0 = dinv[s0];
    float f0[8];
    dec8(m8 + (size_t)s0*HDIM + c, f0);
    #pragma unroll
    for (int j=0;j<8;j++) acc[j] += w0*f0[j];
  }

  #pragma unroll
  for (int j=0;j<8;j++) acc[j] += __shfl_xor(acc[j], 32);

  if (half == 0){
    const size_t base = (size_t)node*HDIM + c;
    float4 S0 = ld4(S + c), S1 = ld4(S + c + 4);
    float4 T0 = ld4(T + c), T1 = ld4(T + c + 4);
    u16x8 hold = *reinterpret_cast<const u16x8*>(h + base);
    float Sv[8] = {S0.x,S0.y,S0.z,S0.w,S1.x,S1.y,S1.z,S1.w};
    float Tv[8] = {T0.x,T0.y,T0.z,T0.w,T1.x,T1.y,T1.z,T1.w};
    u16x8 ob;
    #pragma unroll
    for (int j=0;j<8;j++){
      float o = fmaxf(acc[j]*dn*Sv[j] + Tv[j], 0.f) + bf2f(hold[j]);
      ob[j] = f2bf(o);
    }
    *reinterpret_cast<u16x8*>(h + base) = ob;
  }
}

// ---------------- global mean pool (batch_idx sorted), bf16 h ----------------
__device__ __forceinline__ int lbound(const int* __restrict__ a, int n, int key){
  int lo = 0, hi = n;
  while (lo < hi){ int mid = (lo + hi) >> 1; if (a[mid] < key) lo = mid + 1; else hi = mid; }
  return lo;
}

__global__ __launch_bounds__(128) void k_pool(const unsigned short* __restrict__ h, const int* __restrict__ batch,
                                              float* __restrict__ g){
  int gi = blockIdx.x;
  int lo = lbound(batch, N_NODES, gi);
  int hi = lbound(batch, N_NODES, gi + 1);
  int t = threadIdx.x;
  float s0 = 0.f, s1 = 0.f;
  for (int n = lo; n < hi; ++n){
    unsigned u = *reinterpret_cast<const unsigned*>(h + (size_t)n*HDIM + 2*t);
    s0 += bf2f((unsigned short)(u & 0xffffu));
    s1 += bf2f((unsigned short)(u >> 16));
  }
  float inv = 1.0f / fmaxf((float)(hi - lo), 1.0f);
  g[(size_t)gi*HDIM + 2*t]     = s0 * inv;
  g[(size_t)gi*HDIM + 2*t + 1] = s1 * inv;
}

// ---------------- fused 3-layer property heads, GB graphs per block ----------------
__global__ __launch_bounds__(128) void k_heads(const float* __restrict__ g,
                                               const float* __restrict__ W1, const float* __restrict__ b1,
                                               const float* __restrict__ W2, const float* __restrict__ b2,
                                               const float* __restrict__ W3, const float* __restrict__ b3,
                                               float* __restrict__ out){
  int g0 = blockIdx.x * GB, p = blockIdx.y;
  __shared__ float gs[GB][HDIM];
  __shared__ float z1[GB][128];
  int t = threadIdx.x;
  #pragma unroll
  for (int gi=0; gi<GB; gi++){
    gs[gi][t]       = g[(size_t)(g0+gi)*HDIM + t];
    gs[gi][t + 128] = g[(size_t)(g0+gi)*HDIM + t + 128];
  }
  __syncthreads();

  const float* w1 = W1 + (size_t)p*HDIM*128;
  float a[GB];
  #pragma unroll
  for (int gi=0; gi<GB; gi++) a[gi] = 0.f;
  for (int i=0;i<HDIM;i++){
    float wv = w1[(size_t)i*128 + t];
    #pragma unroll
    for (int gi=0; gi<GB; gi++) a[gi] += gs[gi][i] * wv;
  }
  float b1v = b1[p*128 + t];
  #pragma unroll
  for (int gi=0; gi<GB; gi++) z1[gi][t] = fmaxf(a[gi] + b1v, 0.f);
  __syncthreads();

  if (t < 64){
    const float* w2 = W2 + (size_t)p*128*64;
    float a2[GB];
    #pragma unroll
    for (int gi=0; gi<GB; gi++) a2[gi] = 0.f;
    for (int i=0;i<128;i++){
      float wv = w2[(size_t)i*64 + t];
      #pragma unroll
      for (int gi=0; gi<GB; gi++) a2[gi] += z1[gi][i] * wv;
    }
    float w3v = W3[p*64 + t];
    float b2v = b2[p*64 + t];
    float b3v = b3[p];
    #pragma unroll
    for (int gi=0; gi<GB; gi++){
      float z2 = fmaxf(a2[gi] + b2v, 0.f);
      float v = z2 * w3v;
      #pragma unroll
      for (int off=32; off>0; off>>=1) v += __shfl_down(v, off, 64);
      if (t == 0) out[(size_t)(g0+gi)*NPROPS + p] = v + b3v;
    }
  }
}

// ---------------- launch ----------------
extern "C" void kernel_launch(void* const* d_in, const int* in_sizes, int n_in,
                              void* d_out, int out_size, void* d_ws, size_t ws_size,
                              hipStream_t stream){
  const float* x     = (const float*)d_in[0];
  const int*   ei    = (const int*)  d_in[1];
  const int*   batch = (const int*)  d_in[2];
  const float* embW  = (const float*)d_in[3];
  const float* embb  = (const float*)d_in[4];
  const float* gcnW  = (const float*)d_in[5];
  const float* gcnb  = (const float*)d_in[6];
  const float* bng   = (const float*)d_in[7];
  const float* bnb   = (const float*)d_in[8];
  const float* bnm   = (const float*)d_in[9];
  const float* bnv   = (const float*)d_in[10];
  const float* h1W   = (const float*)d_in[11];
  const float* h1b   = (const float*)d_in[12];
  const float* h2W   = (const float*)d_in[13];
  const float* h2b   = (const float*)d_in[14];
  const float* h3W   = (const float*)d_in[15];
  const float* h3b   = (const float*)d_in[16];
  float* out = (float*)d_out;

  char* w = (char*)d_ws;
  auto alloc = [&](size_t bytes)->char*{ char* p = w; w += (bytes + 255) & ~(size_t)255; return p; };
  unsigned short* h    = (unsigned short*)alloc((size_t)N_NODES*HDIM*2);   // bf16 h
  char*           mbuf =                  alloc((size_t)N_NODES*HDIM);     // xb (bf16) then m8 (fp8)
  int*      rowp = (int*)     alloc((size_t)(N_NODES+1)*4);
  float*    dinv = (float*)   alloc((size_t)N_NODES*4);
  int*      csrs = (int*)     alloc((size_t)N_EDGES*4);
  int*      bktsz= (int*)     alloc(NBKT*4);
  int*      bktbase=(int*)    alloc(NBKT*4);
  unsigned* bkt  = (unsigned*)alloc((size_t)NBKT*BCAP*4);
  float*    gp   = (float*)   alloc((size_t)N_GRAPHS*HDIM*4);
  unsigned short* embWt = (unsigned short*)alloc((size_t)NODE_DIMC*HDIM*2);
  unsigned short* gcnWt = (unsigned short*)alloc((size_t)NLAYERS*HDIM*HDIM*2);
  float* bnS  = (float*)alloc((size_t)NLAYERS*HDIM*4);
  float* bnT  = (float*)alloc((size_t)NLAYERS*HDIM*4);

  unsigned short* xb = (unsigned short*)mbuf;
  unsigned char*  m8 = (unsigned char*)mbuf;

  hipMemsetAsync(bktsz, 0, NBKT*4, stream);

  const int ABLK = (N_EDGES + EPB - 1)/EPB;   // 196
  k_bucketprep<<<ABLK + PREP_BLKS,256,0,stream>>>(ei, bktsz, bkt, x, xb, embW, embWt, gcnW, gcnWt,
                                                  gcnb, bng, bnb, bnm, bnv, bnS, bnT);
  k_bscan<<<1,256,0,stream>>>(bktsz, bktbase, rowp);
  k_bfill<<<NBKT,256,0,stream>>>(bkt, bktsz, bktbase, rowp, dinv, csrs);

  const int RB64 = (N_NODES + 63)/64;   // 782 blocks
  k_mgemm<NODE_DIMC, true><<<RB64,256,0,stream>>>(xb, embWt, embb, h, nullptr, N_NODES);

  for (int l = 0; l < NLAYERS; ++l){
    k_mgemm<HDIM, false><<<RB64,256,0,stream>>>(h, gcnWt + (size_t)l*HDIM*HDIM, nullptr, nullptr, m8, N_NODES);
    k_agg<<<(N_NODES+3)/4,256,0,stream>>>(m8, rowp, csrs, dinv, bnS + l*HDIM, bnT + l*HDIM, h);
  }

  k_pool<<<N_GRAPHS,128,0,stream>>>(h, batch, gp);
  k_heads<<<dim3((N_GRAPHS+GB-1)/GB,NPROPS),128,0,stream>>>(gp, h1W, h1b, h2W, h2b, h3W, h3b, out);
}